// Round 1
// baseline (10789.938 us; speedup 1.0000x reference)
//
#include <hip/hip_runtime.h>
#include <stdint.h>

#define HTABLE (1u << 19)
#define TMASK  (HTABLE - 1u)
#define TILE   64
#define HSTR   68   // padded row stride (floats) for the [256 x 64] h tile

__device__ __forceinline__ float relu_(float v) { return fmaxf(v, 0.f); }

__device__ __constant__ uint32_t PRS[6] = {1u, 2654435761u, 805459861u, 3674653429u, 2097192037u, 1434869437u};
// res_l = floor(16 * (2^(1/3))^l); fp32(2^(1/3)) rounds UP so integer levels floor exactly.
__device__ __constant__ float RESF[16]  = {16.f,20.f,25.f,32.f,40.f,50.f,64.f,80.f,101.f,128.f,161.f,203.f,256.f,322.f,406.f,512.f};
__device__ __constant__ float GRIDF[16] = {1.f/16.f,1.f/20.f,1.f/25.f,1.f/32.f,1.f/40.f,1.f/50.f,1.f/64.f,1.f/80.f,
                                           1.f/101.f,1.f/128.f,1.f/161.f,1.f/203.f,1.f/256.f,1.f/322.f,1.f/406.f,1.f/512.f};

// ---------------- binning kernels ----------------
__global__ void k_count(const int* __restrict__ lid, int n, int* __restrict__ cnt) {
    __shared__ int h4[4];
    int i = blockIdx.x * blockDim.x + threadIdx.x;
    if (threadIdx.x < 4) h4[threadIdx.x] = 0;
    __syncthreads();
    if (i < n) atomicAdd(&h4[lid[i] & 3], 1);
    __syncthreads();
    if (threadIdx.x < 4) atomicAdd(&cnt[threadIdx.x], h4[threadIdx.x]);
}

__global__ void k_offsets(const int* __restrict__ cnt, int* __restrict__ cursor) {
    if (threadIdx.x == 0 && blockIdx.x == 0) {
        int off = 0;
        for (int k = 0; k < 4; k++) {
            cursor[k] = off;
            off = (off + cnt[k] + 63) & ~63;   // pad each class segment to x64
        }
    }
}

__global__ void k_scatter(const int* __restrict__ lid, int n, int* __restrict__ cursor, int* __restrict__ perm) {
    int i = blockIdx.x * blockDim.x + threadIdx.x;
    if (i >= n) return;
    int lane = threadIdx.x & 63;
    int c = lid[i] & 3;
    unsigned long long m0 = __ballot(c == 0), m1 = __ballot(c == 1);
    unsigned long long m2 = __ballot(c == 2), m3 = __ballot(c == 3);
    unsigned long long mc = (c == 0) ? m0 : (c == 1) ? m1 : (c == 2) ? m2 : m3;
    int rank = __popcll(mc & ((1ull << lane) - 1ull));
    int cntl = (lane == 0) ? __popcll(m0) : (lane == 1) ? __popcll(m1) : (lane == 2) ? __popcll(m2) : __popcll(m3);
    int basev = 0;
    if (lane < 4) basev = atomicAdd(&cursor[lane], cntl);
    int base = __shfl(basev, c, 64);
    perm[base + rank] = i;
}

// ---------------- fused encode + MLP ----------------
// Block: 256 threads, 64 points, class-uniform (via perm). LDS h tile [256][HSTR].
__global__ __launch_bounds__(256, 2) void k_fused(
    const float* __restrict__ x, const int* __restrict__ lid, const float* __restrict__ emb,
    const float* __restrict__ W0, const float* __restrict__ b0,
    const float* __restrict__ Wres, const float* __restrict__ bres,
    const float* __restrict__ scales, const float* __restrict__ Wout, const float* __restrict__ bout,
    const int* __restrict__ perm, float* __restrict__ out)
{
    __shared__ float hT[256 * HSTR];     // 69632 B
    __shared__ float encT[32 * HSTR];    //  8704 B (reused as out-layer scratch)
    __shared__ float xl[TILE * 6];       //  1536 B
    __shared__ int   permL[TILE];        //   256 B   total 80128 B -> 2 blocks/CU

    const int t  = threadIdx.x;
    const int p  = t & 63;
    const int lg = t >> 6;

    if (t < TILE) permL[t] = perm[(size_t)blockIdx.x * TILE + t];
    __syncthreads();
    const int g0 = permL[0];
    if (g0 < 0) return;                  // all-padding block
    const int c = lid[g0] & 3;

    for (int idx = t; idx < TILE * 6; idx += 256) {
        int pp = idx / 6, dd = idx - pp * 6;
        int gi = permL[pp]; if (gi < 0) gi = g0;
        float v = x[(size_t)gi * 6 + dd];
        xl[idx] = fminf(fmaxf(v, 0.f), 1.f);
    }
    __syncthreads();

    // ---- encode: wave lg computes levels lg*4..lg*4+3 for all 64 points (its lane = point)
    #pragma unroll
    for (int ii = 0; ii < 4; ii++) {
        const int l = lg * 4 + ii;
        const float res  = RESF[l];
        const float grid = GRIDF[l];
        float wv[6]; uint32_t ua[6], ub[6];
        #pragma unroll
        for (int d = 0; d < 6; d++) {
            float xv  = xl[p * 6 + d];
            float blf = floorf(xv * res);
            float w   = (xv - blf * grid) / (grid + 1e-6f);
            wv[d] = fminf(fmaxf(w, 0.f), 1.f);
            uint32_t uu = (uint32_t)(int)blf * PRS[d];
            ua[d] = uu; ub[d] = uu + PRS[d];
        }
        // v = (i<<4)|(j<<2)|k. Hash: dims (0,1)<-i, (2,3)<-j, (4,5)<-k (MSB-first).
        // Weights: dims (4,5)<-i, (2,3)<-j, (0,1)<-k (LSB-first) — faithful to the reference mismatch.
        uint32_t HI[4], HJ[4], HK[4]; float WI[4], WJ[4], WK[4];
        #pragma unroll
        for (int q = 0; q < 4; q++) {
            const int b1 = (q >> 1) & 1, bb = q & 1;
            HI[q] = (b1 ? ub[0] : ua[0]) ^ (bb ? ub[1] : ua[1]);
            HJ[q] = (b1 ? ub[2] : ua[2]) ^ (bb ? ub[3] : ua[3]);
            HK[q] = (b1 ? ub[4] : ua[4]) ^ (bb ? ub[5] : ua[5]);
            WI[q] = (bb ? wv[4] : 1.f - wv[4]) * (b1 ? wv[5] : 1.f - wv[5]);
            WJ[q] = (bb ? wv[2] : 1.f - wv[2]) * (b1 ? wv[3] : 1.f - wv[3]);
            WK[q] = (bb ? wv[0] : 1.f - wv[0]) * (b1 ? wv[1] : 1.f - wv[1]);
        }
        const float2* __restrict__ embL = reinterpret_cast<const float2*>(emb) + (size_t)l * HTABLE;
        float f0 = 0.f, f1 = 0.f;
        #pragma unroll
        for (int i4 = 0; i4 < 4; i4++) {
            const uint32_t hi = HI[i4]; const float wi = WI[i4];
            #pragma unroll
            for (int j4 = 0; j4 < 4; j4++) {
                const uint32_t hij = hi ^ HJ[j4]; const float wij = wi * WJ[j4];
                #pragma unroll
                for (int k4 = 0; k4 < 4; k4++) {
                    const uint32_t hh = (hij ^ HK[k4]) & TMASK;
                    const float2 e = embL[hh];
                    const float w = wij * WK[k4];
                    f0 = fmaf(w, e.x, f0);
                    f1 = fmaf(w, e.y, f1);
                }
            }
        }
        encT[(2 * l + 0) * HSTR + p] = f0;
        encT[(2 * l + 1) * HSTR + p] = f1;
    }
    __syncthreads();

    // ---- MLP: thread t = neuron t; acc over all 64 points (float4 x 16)
    float4 acc[16];
    float w8[8];

    // layer 0: [64x32] @ [32x256]
    #pragma unroll
    for (int q = 0; q < 16; q++) acc[q] = make_float4(0.f, 0.f, 0.f, 0.f);
    #pragma unroll 1
    for (int k0 = 0; k0 < 32; k0 += 8) {
        #pragma unroll
        for (int kk = 0; kk < 8; kk++) w8[kk] = W0[(size_t)(c * 32 + k0 + kk) * 256 + t];
        #pragma unroll
        for (int q = 0; q < 16; q++) {
            #pragma unroll
            for (int kk = 0; kk < 8; kk++) {
                const float4 hv = *reinterpret_cast<const float4*>(&encT[(k0 + kk) * HSTR + q * 4]);
                acc[q].x = fmaf(hv.x, w8[kk], acc[q].x);
                acc[q].y = fmaf(hv.y, w8[kk], acc[q].y);
                acc[q].z = fmaf(hv.z, w8[kk], acc[q].z);
                acc[q].w = fmaf(hv.w, w8[kk], acc[q].w);
            }
        }
    }
    {
        const float bv = b0[c * 256 + t];
        #pragma unroll
        for (int q = 0; q < 16; q++) {
            float4 o;
            o.x = relu_(acc[q].x + bv); o.y = relu_(acc[q].y + bv);
            o.z = relu_(acc[q].z + bv); o.w = relu_(acc[q].w + bv);
            *reinterpret_cast<float4*>(&hT[t * HSTR + q * 4]) = o;
        }
    }
    __syncthreads();

    // 3 scaled residual blocks: h = s*relu(h@W + b) + h   (in-place, barrier-separated)
    #pragma unroll 1
    for (int ib = 0; ib < 3; ib++) {
        #pragma unroll
        for (int q = 0; q < 16; q++) acc[q] = make_float4(0.f, 0.f, 0.f, 0.f);
        const float* __restrict__ Wl = Wres + (size_t)(c * 3 + ib) * 256 * 256;
        #pragma unroll 1
        for (int k0 = 0; k0 < 256; k0 += 8) {
            #pragma unroll
            for (int kk = 0; kk < 8; kk++) w8[kk] = Wl[(size_t)(k0 + kk) * 256 + t];
            #pragma unroll
            for (int q = 0; q < 16; q++) {
                #pragma unroll
                for (int kk = 0; kk < 8; kk++) {
                    const float4 hv = *reinterpret_cast<const float4*>(&hT[(k0 + kk) * HSTR + q * 4]);
                    acc[q].x = fmaf(hv.x, w8[kk], acc[q].x);
                    acc[q].y = fmaf(hv.y, w8[kk], acc[q].y);
                    acc[q].z = fmaf(hv.z, w8[kk], acc[q].z);
                    acc[q].w = fmaf(hv.w, w8[kk], acc[q].w);
                }
            }
        }
        const float bv = bres[(size_t)(c * 3 + ib) * 256 + t];
        const float sv = scales[c * 3 + ib];
        __syncthreads();   // all reads of hT done before in-place update of own row
        #pragma unroll
        for (int q = 0; q < 16; q++) {
            float4 ho = *reinterpret_cast<const float4*>(&hT[t * HSTR + q * 4]);
            float4 o;
            o.x = fmaf(sv, relu_(acc[q].x + bv), ho.x);
            o.y = fmaf(sv, relu_(acc[q].y + bv), ho.y);
            o.z = fmaf(sv, relu_(acc[q].z + bv), ho.z);
            o.w = fmaf(sv, relu_(acc[q].w + bv), ho.w);
            *reinterpret_cast<float4*>(&hT[t * HSTR + q * 4]) = o;
        }
        __syncthreads();
    }

    // output layer: out[p] = h[:,p] . Wout[c] + bout[c]
    {
        const float* __restrict__ WoL = Wout + c * 256;
        float partial = 0.f;
        const int kbase = lg * 64;
        #pragma unroll 1
        for (int k = kbase; k < kbase + 64; k++)
            partial = fmaf(hT[k * HSTR + p], WoL[k], partial);
        encT[lg * 64 + p] = partial;   // encT reused as scratch
        __syncthreads();
        if (t < TILE) {
            float r = encT[t] + encT[64 + t] + encT[128 + t] + encT[192 + t] + bout[c];
            const int gi = permL[t];
            if (gi >= 0) out[gi] = r;
        }
    }
}

extern "C" void kernel_launch(void* const* d_in, const int* in_sizes, int n_in,
                              void* d_out, int out_size, void* d_ws, size_t ws_size,
                              hipStream_t stream) {
    const float* x      = (const float*)d_in[0];
    const int*   lid    = (const int*)  d_in[1];
    const float* emb    = (const float*)d_in[2];
    const float* W0     = (const float*)d_in[3];
    const float* b0     = (const float*)d_in[4];
    const float* Wres   = (const float*)d_in[5];
    const float* bres   = (const float*)d_in[6];
    const float* scales = (const float*)d_in[7];
    const float* Wout   = (const float*)d_in[8];
    const float* bout   = (const float*)d_in[9];
    float* out = (float*)d_out;

    const int B = in_sizes[1];                 // 524288 points
    int* cnt    = (int*)d_ws;                  // [0..3] class counts
    int* cursor = cnt + 4;                     // [4..7] padded cursors
    int* perm   = cnt + 64;                    // ws + 256 B, padded permutation
    const int nblk = B / TILE + 4;             // 8196: covers worst-case per-class x64 padding

    hipMemsetAsync(d_ws, 0, 32, stream);
    hipMemsetAsync(perm, 0xFF, (size_t)nblk * TILE * sizeof(int), stream);  // -1 fillers
    k_count  <<<B / 256, 256, 0, stream>>>(lid, B, cnt);
    k_offsets<<<1, 64, 0, stream>>>(cnt, cursor);
    k_scatter<<<B / 256, 256, 0, stream>>>(lid, B, cursor, perm);
    k_fused  <<<nblk, 256, 0, stream>>>(x, lid, emb, W0, b0, Wres, bres, scales, Wout, bout, perm, out);
}

// Round 2
// 6502.229 us; speedup vs baseline: 1.6594x; 1.6594x over previous
//
#include <hip/hip_runtime.h>
#include <stdint.h>

#define HTABLE (1u << 19)
#define TMASK  (HTABLE - 1u)
#define TILE   64
#define HSTR   68   // padded row stride (floats) for the [256 x 64] h tile

__device__ __forceinline__ float relu_(float v) { return fmaxf(v, 0.f); }

// bf16 pack/unpack (RNE), bit-level to avoid header type friction
__device__ __forceinline__ uint32_t f2bf(float f) {
    uint32_t u = __float_as_uint(f);
    return (u + 0x7FFFu + ((u >> 16) & 1u)) >> 16;
}
__device__ __forceinline__ float bf2f(uint32_t h) { return __uint_as_float(h << 16); }

__device__ __constant__ uint32_t PRS[6] = {1u, 2654435761u, 805459861u, 3674653429u, 2097192037u, 1434869437u};
// res_l = floor(16 * (2^(1/3))^l); fp32(2^(1/3)) rounds UP so integer levels floor exactly.
__device__ __constant__ float RESF[16]  = {16.f,20.f,25.f,32.f,40.f,50.f,64.f,80.f,101.f,128.f,161.f,203.f,256.f,322.f,406.f,512.f};
__device__ __constant__ float GRIDF[16] = {1.f/16.f,1.f/20.f,1.f/25.f,1.f/32.f,1.f/40.f,1.f/50.f,1.f/64.f,1.f/80.f,
                                           1.f/101.f,1.f/128.f,1.f/161.f,1.f/203.f,1.f/256.f,1.f/322.f,1.f/406.f,1.f/512.f};

// ---------------- binning kernels ----------------
__global__ void k_count(const int* __restrict__ lid, int n, int* __restrict__ cnt) {
    __shared__ int h4[4];
    int i = blockIdx.x * blockDim.x + threadIdx.x;
    if (threadIdx.x < 4) h4[threadIdx.x] = 0;
    __syncthreads();
    if (i < n) atomicAdd(&h4[lid[i] & 3], 1);
    __syncthreads();
    if (threadIdx.x < 4) atomicAdd(&cnt[threadIdx.x], h4[threadIdx.x]);
}

__global__ void k_offsets(const int* __restrict__ cnt, int* __restrict__ cursor) {
    if (threadIdx.x == 0 && blockIdx.x == 0) {
        int off = 0;
        for (int k = 0; k < 4; k++) {
            cursor[k] = off;
            off = (off + cnt[k] + 63) & ~63;   // pad each class segment to x64
        }
    }
}

__global__ void k_scatter(const int* __restrict__ lid, int n, int* __restrict__ cursor, int* __restrict__ perm) {
    int i = blockIdx.x * blockDim.x + threadIdx.x;
    if (i >= n) return;
    int lane = threadIdx.x & 63;
    int c = lid[i] & 3;
    unsigned long long m0 = __ballot(c == 0), m1 = __ballot(c == 1);
    unsigned long long m2 = __ballot(c == 2), m3 = __ballot(c == 3);
    unsigned long long mc = (c == 0) ? m0 : (c == 1) ? m1 : (c == 2) ? m2 : m3;
    int rank = __popcll(mc & ((1ull << lane) - 1ull));
    int cntl = (lane == 0) ? __popcll(m0) : (lane == 1) ? __popcll(m1) : (lane == 2) ? __popcll(m2) : __popcll(m3);
    int basev = 0;
    if (lane < 4) basev = atomicAdd(&cursor[lane], cntl);
    int base = __shfl(basev, c, 64);
    perm[base + rank] = i;
}

// ---------------- encode kernel: one level per block, level -> XCD pinned ----------------
// Grid = 2 passes x 8 levels x (B/256) chunks. blockIdx % 8 == level % 8 -> under
// round-robin block->XCD dispatch, XCD k only touches table k (4 MB == its L2).
// Pass 0 = levels 0..7, pass 1 = levels 8..15 (dispatched after, temporal separation).
__global__ __launch_bounds__(256, 4) void k_encode(
    const float* __restrict__ x, const float* __restrict__ emb,
    uint32_t* __restrict__ encP, int B)
{
    __shared__ float xs[256 * 6];
    const int t = threadIdx.x;
    const int NC8 = (B >> 8) << 3;               // blocks per pass
    const int pass = (blockIdx.x >= NC8) ? 1 : 0;
    const int rem  = blockIdx.x - pass * NC8;
    const int l    = (rem & 7) + (pass << 3);
    const int chunk = rem >> 3;
    const int pbase = chunk << 8;                // first point of this block

    for (int idx = t; idx < 256 * 6; idx += 256) {
        float v = x[(size_t)pbase * 6 + idx];
        xs[idx] = fminf(fmaxf(v, 0.f), 1.f);
    }
    __syncthreads();

    const float res  = RESF[l];
    const float grid = GRIDF[l];
    float wv[6]; uint32_t ua[6], ub[6];
    #pragma unroll
    for (int d = 0; d < 6; d++) {
        float xv  = xs[t * 6 + d];
        float blf = floorf(xv * res);
        float w   = (xv - blf * grid) / (grid + 1e-6f);
        wv[d] = fminf(fmaxf(w, 0.f), 1.f);
        uint32_t uu = (uint32_t)(int)blf * PRS[d];
        ua[d] = uu; ub[d] = uu + PRS[d];
    }
    // v = (i<<4)|(j<<2)|k. Hash: dims (0,1)<-i, (2,3)<-j, (4,5)<-k (MSB-first).
    // Weights: dims (4,5)<-i, (2,3)<-j, (0,1)<-k (LSB-first) — faithful to the reference mismatch.
    uint32_t HI[4], HJ[4], HK[4]; float WI[4], WJ[4], WK[4];
    #pragma unroll
    for (int q = 0; q < 4; q++) {
        const int b1 = (q >> 1) & 1, bb = q & 1;
        HI[q] = (b1 ? ub[0] : ua[0]) ^ (bb ? ub[1] : ua[1]);
        HJ[q] = (b1 ? ub[2] : ua[2]) ^ (bb ? ub[3] : ua[3]);
        HK[q] = (b1 ? ub[4] : ua[4]) ^ (bb ? ub[5] : ua[5]);
        WI[q] = (bb ? wv[4] : 1.f - wv[4]) * (b1 ? wv[5] : 1.f - wv[5]);
        WJ[q] = (bb ? wv[2] : 1.f - wv[2]) * (b1 ? wv[3] : 1.f - wv[3]);
        WK[q] = (bb ? wv[0] : 1.f - wv[0]) * (b1 ? wv[1] : 1.f - wv[1]);
    }
    const float2* __restrict__ embL = reinterpret_cast<const float2*>(emb) + (size_t)l * HTABLE;
    float f0 = 0.f, f1 = 0.f;
    #pragma unroll
    for (int i4 = 0; i4 < 4; i4++) {
        const uint32_t hi = HI[i4]; const float wi = WI[i4];
        #pragma unroll
        for (int j4 = 0; j4 < 4; j4++) {
            const uint32_t hij = hi ^ HJ[j4]; const float wij = wi * WJ[j4];
            #pragma unroll
            for (int k4 = 0; k4 < 4; k4++) {
                const uint32_t hh = (hij ^ HK[k4]) & TMASK;
                const float2 e = embL[hh];
                const float w = wij * WK[k4];
                f0 = fmaf(w, e.x, f0);
                f1 = fmaf(w, e.y, f1);
            }
        }
    }
    encP[(size_t)l * B + pbase + t] = f2bf(f0) | (f2bf(f1) << 16);
}

// ---------------- MLP kernel ----------------
// Block: 256 threads, 64 points, class-uniform (via perm). LDS h tile [256][HSTR].
__global__ __launch_bounds__(256, 2) void k_mlp(
    const int* __restrict__ lid, const uint32_t* __restrict__ encP,
    const float* __restrict__ W0, const float* __restrict__ b0,
    const float* __restrict__ Wres, const float* __restrict__ bres,
    const float* __restrict__ scales, const float* __restrict__ Wout, const float* __restrict__ bout,
    const int* __restrict__ perm, float* __restrict__ out, int B)
{
    __shared__ float hT[256 * HSTR];     // 69632 B
    __shared__ float encT[32 * HSTR];    //  8704 B (enc staging; reused as out-layer scratch)
    __shared__ int   permL[TILE];

    const int t  = threadIdx.x;
    const int p  = t & 63;
    const int lg = t >> 6;

    if (t < TILE) permL[t] = perm[(size_t)blockIdx.x * TILE + t];
    __syncthreads();
    const int g0 = permL[0];
    if (g0 < 0) return;                  // all-padding block
    const int c = lid[g0] & 3;

    // stage encoded features: [32 features][64 points]
    for (int idx = t; idx < 16 * 64; idx += 256) {
        const int l = idx >> 6, pp = idx & 63;
        const int gi = permL[pp];
        const uint32_t v = (gi >= 0) ? encP[(size_t)l * B + gi] : 0u;
        encT[(2 * l + 0) * HSTR + pp] = bf2f(v & 0xFFFFu);
        encT[(2 * l + 1) * HSTR + pp] = bf2f(v >> 16);
    }
    __syncthreads();

    // ---- MLP: thread t = neuron t; acc over all 64 points (float4 x 16)
    float4 acc[16];
    float w8[8];

    // layer 0: [64x32] @ [32x256]
    #pragma unroll
    for (int q = 0; q < 16; q++) acc[q] = make_float4(0.f, 0.f, 0.f, 0.f);
    #pragma unroll 1
    for (int k0 = 0; k0 < 32; k0 += 8) {
        #pragma unroll
        for (int kk = 0; kk < 8; kk++) w8[kk] = W0[(size_t)(c * 32 + k0 + kk) * 256 + t];
        #pragma unroll
        for (int q = 0; q < 16; q++) {
            #pragma unroll
            for (int kk = 0; kk < 8; kk++) {
                const float4 hv = *reinterpret_cast<const float4*>(&encT[(k0 + kk) * HSTR + q * 4]);
                acc[q].x = fmaf(hv.x, w8[kk], acc[q].x);
                acc[q].y = fmaf(hv.y, w8[kk], acc[q].y);
                acc[q].z = fmaf(hv.z, w8[kk], acc[q].z);
                acc[q].w = fmaf(hv.w, w8[kk], acc[q].w);
            }
        }
    }
    {
        const float bv = b0[c * 256 + t];
        #pragma unroll
        for (int q = 0; q < 16; q++) {
            float4 o;
            o.x = relu_(acc[q].x + bv); o.y = relu_(acc[q].y + bv);
            o.z = relu_(acc[q].z + bv); o.w = relu_(acc[q].w + bv);
            *reinterpret_cast<float4*>(&hT[t * HSTR + q * 4]) = o;
        }
    }
    __syncthreads();

    // 3 scaled residual blocks: h = s*relu(h@W + b) + h   (in-place, barrier-separated)
    #pragma unroll 1
    for (int ib = 0; ib < 3; ib++) {
        #pragma unroll
        for (int q = 0; q < 16; q++) acc[q] = make_float4(0.f, 0.f, 0.f, 0.f);
        const float* __restrict__ Wl = Wres + (size_t)(c * 3 + ib) * 256 * 256;
        #pragma unroll 1
        for (int k0 = 0; k0 < 256; k0 += 8) {
            #pragma unroll
            for (int kk = 0; kk < 8; kk++) w8[kk] = Wl[(size_t)(k0 + kk) * 256 + t];
            #pragma unroll
            for (int q = 0; q < 16; q++) {
                #pragma unroll
                for (int kk = 0; kk < 8; kk++) {
                    const float4 hv = *reinterpret_cast<const float4*>(&hT[(k0 + kk) * HSTR + q * 4]);
                    acc[q].x = fmaf(hv.x, w8[kk], acc[q].x);
                    acc[q].y = fmaf(hv.y, w8[kk], acc[q].y);
                    acc[q].z = fmaf(hv.z, w8[kk], acc[q].z);
                    acc[q].w = fmaf(hv.w, w8[kk], acc[q].w);
                }
            }
        }
        const float bv = bres[(size_t)(c * 3 + ib) * 256 + t];
        const float sv = scales[c * 3 + ib];
        __syncthreads();   // all reads of hT done before in-place update of own row
        #pragma unroll
        for (int q = 0; q < 16; q++) {
            float4 ho = *reinterpret_cast<const float4*>(&hT[t * HSTR + q * 4]);
            float4 o;
            o.x = fmaf(sv, relu_(acc[q].x + bv), ho.x);
            o.y = fmaf(sv, relu_(acc[q].y + bv), ho.y);
            o.z = fmaf(sv, relu_(acc[q].z + bv), ho.z);
            o.w = fmaf(sv, relu_(acc[q].w + bv), ho.w);
            *reinterpret_cast<float4*>(&hT[t * HSTR + q * 4]) = o;
        }
        __syncthreads();
    }

    // output layer: out[p] = h[:,p] . Wout[c] + bout[c]
    {
        const float* __restrict__ WoL = Wout + c * 256;
        float partial = 0.f;
        const int kbase = lg * 64;
        #pragma unroll 1
        for (int k = kbase; k < kbase + 64; k++)
            partial = fmaf(hT[k * HSTR + p], WoL[k], partial);
        encT[lg * 64 + p] = partial;   // encT reused as scratch
        __syncthreads();
        if (t < TILE) {
            float r = encT[t] + encT[64 + t] + encT[128 + t] + encT[192 + t] + bout[c];
            const int gi = permL[t];
            if (gi >= 0) out[gi] = r;
        }
    }
}

extern "C" void kernel_launch(void* const* d_in, const int* in_sizes, int n_in,
                              void* d_out, int out_size, void* d_ws, size_t ws_size,
                              hipStream_t stream) {
    const float* x      = (const float*)d_in[0];
    const int*   lid    = (const int*)  d_in[1];
    const float* emb    = (const float*)d_in[2];
    const float* W0     = (const float*)d_in[3];
    const float* b0     = (const float*)d_in[4];
    const float* Wres   = (const float*)d_in[5];
    const float* bres   = (const float*)d_in[6];
    const float* scales = (const float*)d_in[7];
    const float* Wout   = (const float*)d_in[8];
    const float* bout   = (const float*)d_in[9];
    float* out = (float*)d_out;

    const int B = in_sizes[1];                 // 524288 points
    int* cnt    = (int*)d_ws;                  // [0..3] class counts
    int* cursor = cnt + 4;                     // [4..7] padded cursors
    int* perm   = cnt + 64;                    // ws + 256 B, padded permutation
    uint32_t* encP = (uint32_t*)((char*)d_ws + (4u << 20));   // ws+4MB: [16][B] packed bf16 pairs (32 MB)
    const int nblk = B / TILE + 4;             // 8196: covers worst-case per-class x64 padding

    hipMemsetAsync(d_ws, 0, 32, stream);
    hipMemsetAsync(perm, 0xFF, (size_t)nblk * TILE * sizeof(int), stream);  // -1 fillers
    k_count  <<<B / 256, 256, 0, stream>>>(lid, B, cnt);
    k_offsets<<<1, 64, 0, stream>>>(cnt, cursor);
    k_scatter<<<B / 256, 256, 0, stream>>>(lid, B, cursor, perm);
    k_encode <<<(B / 256) * 16, 256, 0, stream>>>(x, emb, encP, B);
    k_mlp    <<<nblk, 256, 0, stream>>>(lid, encP, W0, b0, Wres, bres, scales, Wout, bout, perm, out, B);
}

// Round 4
// 2798.626 us; speedup vs baseline: 3.8554x; 2.3234x over previous
//
#include <hip/hip_runtime.h>
#include <stdint.h>

#define HTABLE (1u << 19)
#define TMASK  (HTABLE - 1u)
#define TILE   64
#define KSTR   264   // hB row stride in bf16 elems (528 B: 16B-aligned, 2-way-free banks)
#define KE     40    // encB row stride in bf16 elems

typedef __attribute__((ext_vector_type(8))) short short8;
typedef __attribute__((ext_vector_type(4))) float floatx4;

__device__ __forceinline__ float relu_(float v) { return fmaxf(v, 0.f); }

__device__ __forceinline__ uint32_t f2bf(float f) {
    uint32_t u = __float_as_uint(f);
    return (u + 0x7FFFu + ((u >> 16) & 1u)) >> 16;
}
__device__ __forceinline__ float bf2f(uint32_t h) { return __uint_as_float(h << 16); }

__device__ __constant__ uint32_t PRS[6] = {1u, 2654435761u, 805459861u, 3674653429u, 2097192037u, 1434869437u};
__device__ __constant__ float RESF[16]  = {16.f,20.f,25.f,32.f,40.f,50.f,64.f,80.f,101.f,128.f,161.f,203.f,256.f,322.f,406.f,512.f};
__device__ __constant__ float GRIDF[16] = {1.f/16.f,1.f/20.f,1.f/25.f,1.f/32.f,1.f/40.f,1.f/50.f,1.f/64.f,1.f/80.f,
                                           1.f/101.f,1.f/128.f,1.f/161.f,1.f/203.f,1.f/256.f,1.f/322.f,1.f/406.f,1.f/512.f};

// ---------------- binning kernels ----------------
__global__ void k_count(const int* __restrict__ lid, int n, int* __restrict__ cnt) {
    __shared__ int h4[4];
    int i = blockIdx.x * blockDim.x + threadIdx.x;
    if (threadIdx.x < 4) h4[threadIdx.x] = 0;
    __syncthreads();
    if (i < n) atomicAdd(&h4[lid[i] & 3], 1);
    __syncthreads();
    if (threadIdx.x < 4) atomicAdd(&cnt[threadIdx.x], h4[threadIdx.x]);
}

__global__ void k_offsets(const int* __restrict__ cnt, int* __restrict__ cursor) {
    if (threadIdx.x == 0 && blockIdx.x == 0) {
        int off = 0;
        for (int k = 0; k < 4; k++) {
            cursor[k] = off;
            off = (off + cnt[k] + 63) & ~63;
        }
    }
}

__global__ void k_scatter(const int* __restrict__ lid, int n, int* __restrict__ cursor, int* __restrict__ perm) {
    int i = blockIdx.x * blockDim.x + threadIdx.x;
    if (i >= n) return;
    int lane = threadIdx.x & 63;
    int c = lid[i] & 3;
    unsigned long long m0 = __ballot(c == 0), m1 = __ballot(c == 1);
    unsigned long long m2 = __ballot(c == 2), m3 = __ballot(c == 3);
    unsigned long long mc = (c == 0) ? m0 : (c == 1) ? m1 : (c == 2) ? m2 : m3;
    int rank = __popcll(mc & ((1ull << lane) - 1ull));
    int cntl = (lane == 0) ? __popcll(m0) : (lane == 1) ? __popcll(m1) : (lane == 2) ? __popcll(m2) : __popcll(m3);
    int basev = 0;
    if (lane < 4) basev = atomicAdd(&cursor[lane], cntl);
    int base = __shfl(basev, c, 64);
    perm[base + rank] = i;
}

// ---------------- weight prep: transpose + bf16 ----------------
// blocks 0..191: Wres [c][ib][k][n] fp32 -> Wrt [c][ib][n][k] bf16 (64x64 tiles)
// blocks 192..195: W0 [c][32][256] fp32 -> W0t [c][256][32] bf16
__global__ __launch_bounds__(256) void k_prep(const float* __restrict__ Wres, const float* __restrict__ W0,
                                              uint16_t* __restrict__ Wrt, uint16_t* __restrict__ W0t) {
    __shared__ float sm[64 * 65 > 32 * 257 ? 64 * 65 : 32 * 257];
    const int t = threadIdx.x;
    const int bid = blockIdx.x;
    if (bid < 192) {
        const int c = bid / 48, rem = bid % 48, ib = rem / 16, tile = rem % 16;
        const int n0 = (tile / 4) * 64, k0 = (tile % 4) * 64;
        const float* src = Wres + (size_t)(c * 3 + ib) * 65536;
        for (int i = 0; i < 16; i++) {
            int idx = t + 256 * i, r = idx >> 6, cc = idx & 63;
            sm[r * 65 + cc] = src[(size_t)(k0 + r) * 256 + n0 + cc];
        }
        __syncthreads();
        uint16_t* dst = Wrt + (size_t)(c * 3 + ib) * 65536;
        for (int i = 0; i < 16; i++) {
            int idx = t + 256 * i, rn = idx >> 6, ck = idx & 63;
            dst[(size_t)(n0 + rn) * 256 + k0 + ck] = (uint16_t)f2bf(sm[ck * 65 + rn]);
        }
    } else {
        const int c = bid - 192;
        for (int i = 0; i < 32; i++) {
            int idx = t + 256 * i, k = idx >> 8, n = idx & 255;
            sm[k * 257 + n] = W0[(size_t)c * 8192 + idx];
        }
        __syncthreads();
        for (int i = 0; i < 32; i++) {
            int idx = t + 256 * i, n = idx >> 5, k = idx & 31;
            W0t[(size_t)c * 8192 + idx] = (uint16_t)f2bf(sm[k * 257 + n]);
        }
    }
}

// ---------------- encode kernel: one level per block, level -> XCD pinned ----------------
__global__ __launch_bounds__(256, 4) void k_encode(
    const float* __restrict__ x, const float* __restrict__ emb,
    uint32_t* __restrict__ encP, int B)
{
    __shared__ float xs[256 * 6];
    const int t = threadIdx.x;
    const int NC8 = (B >> 8) << 3;
    const int pass = (blockIdx.x >= NC8) ? 1 : 0;
    const int rem  = blockIdx.x - pass * NC8;
    const int l    = (rem & 7) + (pass << 3);
    const int chunk = rem >> 3;
    const int pbase = chunk << 8;

    for (int idx = t; idx < 256 * 6; idx += 256) {
        float v = x[(size_t)pbase * 6 + idx];
        xs[idx] = fminf(fmaxf(v, 0.f), 1.f);
    }
    __syncthreads();

    const float res  = RESF[l];
    const float grid = GRIDF[l];
    float wv[6]; uint32_t ua[6], ub[6];
    #pragma unroll
    for (int d = 0; d < 6; d++) {
        float xv  = xs[t * 6 + d];
        float blf = floorf(xv * res);
        float w   = (xv - blf * grid) / (grid + 1e-6f);
        wv[d] = fminf(fmaxf(w, 0.f), 1.f);
        uint32_t uu = (uint32_t)(int)blf * PRS[d];
        ua[d] = uu; ub[d] = uu + PRS[d];
    }
    // v = (i<<4)|(j<<2)|k. Hash: dims (0,1)<-i, (2,3)<-j, (4,5)<-k (MSB-first).
    // Weights: dims (4,5)<-i, (2,3)<-j, (0,1)<-k (LSB-first) — faithful to the reference mismatch.
    uint32_t HI[4], HJ[4], HK[4]; float WI[4], WJ[4], WK[4];
    #pragma unroll
    for (int q = 0; q < 4; q++) {
        const int b1 = (q >> 1) & 1, bb = q & 1;
        HI[q] = (b1 ? ub[0] : ua[0]) ^ (bb ? ub[1] : ua[1]);
        HJ[q] = (b1 ? ub[2] : ua[2]) ^ (bb ? ub[3] : ua[3]);
        HK[q] = (b1 ? ub[4] : ua[4]) ^ (bb ? ub[5] : ua[5]);
        WI[q] = (bb ? wv[4] : 1.f - wv[4]) * (b1 ? wv[5] : 1.f - wv[5]);
        WJ[q] = (bb ? wv[2] : 1.f - wv[2]) * (b1 ? wv[3] : 1.f - wv[3]);
        WK[q] = (bb ? wv[0] : 1.f - wv[0]) * (b1 ? wv[1] : 1.f - wv[1]);
    }
    const float2* __restrict__ embL = reinterpret_cast<const float2*>(emb) + (size_t)l * HTABLE;
    float f0 = 0.f, f1 = 0.f;
    #pragma unroll
    for (int i4 = 0; i4 < 4; i4++) {
        const uint32_t hi = HI[i4]; const float wi = WI[i4];
        #pragma unroll
        for (int j4 = 0; j4 < 4; j4++) {
            const uint32_t hij = hi ^ HJ[j4]; const float wij = wi * WJ[j4];
            #pragma unroll
            for (int k4 = 0; k4 < 4; k4++) {
                const uint32_t hh = (hij ^ HK[k4]) & TMASK;
                const float2 e = embL[hh];
                const float w = wij * WK[k4];
                f0 = fmaf(w, e.x, f0);
                f1 = fmaf(w, e.y, f1);
            }
        }
    }
    encP[(size_t)l * B + pbase + t] = f2bf(f0) | (f2bf(f1) << 16);
}

// ---------------- MFMA MLP ----------------
// Per block: 64 class-uniform points. GEMMs computed as D[n=neuron][m=point] = W^T . H
// so C/D regs (4 consecutive neurons) are k-contiguous for the next layer's B operand.
// Wave wv owns neurons [wv*64, wv*64+64); fp32 residual carry lives in h_reg.
__global__ __launch_bounds__(256, 2) void k_mlp2(
    const int* __restrict__ lid, const uint32_t* __restrict__ encP,
    const uint16_t* __restrict__ W0t, const float* __restrict__ b0,
    const uint16_t* __restrict__ Wrt, const float* __restrict__ bres,
    const float* __restrict__ scales, const float* __restrict__ Wout, const float* __restrict__ bout,
    const int* __restrict__ perm, float* __restrict__ out, int B)
{
    __shared__ uint16_t hB[64 * KSTR];     // 33792 B  H as [point][k] bf16
    __shared__ uint16_t encB[64 * KE];     //  5120 B  enc as [point][k32] bf16
    __shared__ float    bs[256];           //  per-layer bias / Wout stage
    __shared__ float    outP[256];
    __shared__ int      permL[TILE];

    const int t  = threadIdx.x;
    const int lane = t & 63;
    const int wv = t >> 6;          // wave id: neuron slice
    const int mi = lane & 15;       // point within 16-col
    const int q  = lane >> 4;       // quad

    if (t < TILE) permL[t] = perm[(size_t)blockIdx.x * TILE + t];
    __syncthreads();
    const int g0 = permL[0];
    if (g0 < 0) return;
    const int c = lid[g0] & 3;

    // stage enc [point][k=2l..2l+1] and b0
    bs[t] = b0[c * 256 + t];
    for (int idx = t; idx < 16 * 64; idx += 256) {
        const int l = idx >> 6, pp = idx & 63;
        const int gi = permL[pp];
        ((uint32_t*)encB)[pp * (KE / 2) + l] = (gi >= 0) ? encP[(size_t)l * B + gi] : 0u;
    }
    __syncthreads();

    floatx4 acc[4][4];
    floatx4 h_reg[4][4];

    // ---- layer 0: D = W0^T(256x32) . enc(32x64)
    {
        #pragma unroll
        for (int mt = 0; mt < 4; mt++)
            #pragma unroll
            for (int nt = 0; nt < 4; nt++) acc[mt][nt] = (floatx4){0.f, 0.f, 0.f, 0.f};
        const short8* Wp = (const short8*)(W0t + (size_t)c * 8192);
        short8 A[4], Bf[4];
        #pragma unroll
        for (int mt = 0; mt < 4; mt++) A[mt] = Wp[(wv * 64 + mt * 16 + mi) * 4 + q];
        #pragma unroll
        for (int nt = 0; nt < 4; nt++) Bf[nt] = *(const short8*)&encB[(nt * 16 + mi) * KE + q * 8];
        #pragma unroll
        for (int mt = 0; mt < 4; mt++)
            #pragma unroll
            for (int nt = 0; nt < 4; nt++)
                acc[mt][nt] = __builtin_amdgcn_mfma_f32_16x16x32_bf16(A[mt], Bf[nt], acc[mt][nt], 0, 0, 0);
        // h = relu(u + b0); write bf16 to hB
        #pragma unroll
        for (int mt = 0; mt < 4; mt++) {
            const int nb = wv * 64 + mt * 16 + q * 4;
            #pragma unroll
            for (int nt = 0; nt < 4; nt++) {
                floatx4 u = acc[mt][nt], h;
                h[0] = relu_(u[0] + bs[nb + 0]); h[1] = relu_(u[1] + bs[nb + 1]);
                h[2] = relu_(u[2] + bs[nb + 2]); h[3] = relu_(u[3] + bs[nb + 3]);
                h_reg[mt][nt] = h;
                uint2 pk; pk.x = f2bf(h[0]) | (f2bf(h[1]) << 16); pk.y = f2bf(h[2]) | (f2bf(h[3]) << 16);
                *(uint2*)&hB[(nt * 16 + mi) * KSTR + nb] = pk;
            }
        }
    }
    __syncthreads();

    // ---- 3 scaled residual blocks
    #pragma unroll 1
    for (int ib = 0; ib < 3; ib++) {
        bs[t] = bres[(size_t)((c * 3 + ib) << 8) + t];   // read after the post-MFMA barrier
        const float s = scales[c * 3 + ib];
        #pragma unroll
        for (int mt = 0; mt < 4; mt++)
            #pragma unroll
            for (int nt = 0; nt < 4; nt++) acc[mt][nt] = (floatx4){0.f, 0.f, 0.f, 0.f};

        const short8* Wp = (const short8*)(Wrt + (size_t)(c * 3 + ib) * 65536);
        short8 Acur[4], Anext[4], Bf[4];
        #pragma unroll
        for (int mt = 0; mt < 4; mt++) Acur[mt] = Wp[(wv * 64 + mt * 16 + mi) * 32 + q];
        #pragma unroll 1
        for (int ks = 0; ks < 8; ks++) {
            #pragma unroll
            for (int nt = 0; nt < 4; nt++)
                Bf[nt] = *(const short8*)&hB[(nt * 16 + mi) * KSTR + ks * 32 + q * 8];
            if (ks < 7) {
                #pragma unroll
                for (int mt = 0; mt < 4; mt++)
                    Anext[mt] = Wp[(wv * 64 + mt * 16 + mi) * 32 + (ks + 1) * 4 + q];
            }
            #pragma unroll
            for (int mt = 0; mt < 4; mt++)
                #pragma unroll
                for (int nt = 0; nt < 4; nt++)
                    acc[mt][nt] = __builtin_amdgcn_mfma_f32_16x16x32_bf16(Acur[mt], Bf[nt], acc[mt][nt], 0, 0, 0);
            #pragma unroll
            for (int mt = 0; mt < 4; mt++) Acur[mt] = Anext[mt];
        }
        __syncthreads();   // hB reads done; bs staged
        #pragma unroll
        for (int mt = 0; mt < 4; mt++) {
            const int nb = wv * 64 + mt * 16 + q * 4;
            #pragma unroll
            for (int nt = 0; nt < 4; nt++) {
                floatx4 u = acc[mt][nt];
                floatx4 h = h_reg[mt][nt];
                h[0] = fmaf(s, relu_(u[0] + bs[nb + 0]), h[0]);
                h[1] = fmaf(s, relu_(u[1] + bs[nb + 1]), h[1]);
                h[2] = fmaf(s, relu_(u[2] + bs[nb + 2]), h[2]);
                h[3] = fmaf(s, relu_(u[3] + bs[nb + 3]), h[3]);
                h_reg[mt][nt] = h;
                if (ib < 2) {
                    uint2 pk; pk.x = f2bf(h[0]) | (f2bf(h[1]) << 16); pk.y = f2bf(h[2]) | (f2bf(h[3]) << 16);
                    *(uint2*)&hB[(nt * 16 + mi) * KSTR + nb] = pk;
                }
            }
        }
        if (ib < 2) __syncthreads();
    }

    // ---- output layer: out[p] = sum_n h[n][p] * Wout[n] + bout
    __syncthreads();
    bs[t] = Wout[c * 256 + t];
    __syncthreads();
    float po[4] = {0.f, 0.f, 0.f, 0.f};
    #pragma unroll
    for (int mt = 0; mt < 4; mt++) {
        const int nb = wv * 64 + mt * 16 + q * 4;
        const float w0v = bs[nb + 0], w1v = bs[nb + 1], w2v = bs[nb + 2], w3v = bs[nb + 3];
        #pragma unroll
        for (int nt = 0; nt < 4; nt++) {
            const floatx4 h = h_reg[mt][nt];
            po[nt] += h[0] * w0v + h[1] * w1v + h[2] * w2v + h[3] * w3v;
        }
    }
    #pragma unroll
    for (int nt = 0; nt < 4; nt++) {
        float v = po[nt];
        v += __shfl_xor(v, 16, 64);
        v += __shfl_xor(v, 32, 64);
        if (q == 0) outP[wv * 64 + nt * 16 + mi] = v;
    }
    __syncthreads();
    if (t < TILE) {
        float r = outP[t] + outP[64 + t] + outP[128 + t] + outP[192 + t] + bout[c];
        const int gi = permL[t];
        if (gi >= 0) out[gi] = r;
    }
}

extern "C" void kernel_launch(void* const* d_in, const int* in_sizes, int n_in,
                              void* d_out, int out_size, void* d_ws, size_t ws_size,
                              hipStream_t stream) {
    const float* x      = (const float*)d_in[0];
    const int*   lid    = (const int*)  d_in[1];
    const float* emb    = (const float*)d_in[2];
    const float* W0     = (const float*)d_in[3];
    const float* b0     = (const float*)d_in[4];
    const float* Wres   = (const float*)d_in[5];
    const float* bres   = (const float*)d_in[6];
    const float* scales = (const float*)d_in[7];
    const float* Wout   = (const float*)d_in[8];
    const float* bout   = (const float*)d_in[9];
    float* out = (float*)d_out;

    const int B = in_sizes[1];                          // 524288 points
    int* cnt    = (int*)d_ws;                           // [0..3]
    int* cursor = cnt + 4;                              // [4..7]
    int* perm   = cnt + 64;                             // +256 B, padded permutation (~2.1 MB)
    uint16_t* W0t = (uint16_t*)((char*)d_ws + 2228224); // +2.125 MB: [4][256][32] bf16 (64 KB)
    uint16_t* Wrt = (uint16_t*)((char*)d_ws + 2359296); // +2.25 MB: [4][3][256][256] bf16 (1.5 MB)
    uint32_t* encP = (uint32_t*)((char*)d_ws + (4u << 20)); // +4 MB: [16][B] packed bf16 pairs (32 MB)
    const int nblk = B / TILE + 4;                      // 8196

    (void)hipMemsetAsync(d_ws, 0, 32, stream);
    (void)hipMemsetAsync(perm, 0xFF, (size_t)nblk * TILE * sizeof(int), stream);
    k_prep   <<<196, 256, 0, stream>>>(Wres, W0, Wrt, W0t);
    k_count  <<<B / 256, 256, 0, stream>>>(lid, B, cnt);
    k_offsets<<<1, 64, 0, stream>>>(cnt, cursor);
    k_scatter<<<B / 256, 256, 0, stream>>>(lid, B, cursor, perm);
    k_encode <<<(B / 256) * 16, 256, 0, stream>>>(x, emb, encP, B);
    k_mlp2   <<<nblk, 256, 0, stream>>>(lid, encP, W0t, b0, Wrt, bres, scales, Wout, bout, perm, out, B);
}

// Round 5
// 1930.866 us; speedup vs baseline: 5.5881x; 1.4494x over previous
//
#include <hip/hip_runtime.h>
#include <stdint.h>

#define HTABLE (1u << 19)
#define TMASK  (HTABLE - 1u)
#define TILE   64
#define KSTR   264   // hB row stride in bf16 elems (528 B: 16B-aligned, 2-way-free banks)
#define KE     40    // encB row stride in bf16 elems

typedef __attribute__((ext_vector_type(8))) short short8;
typedef __attribute__((ext_vector_type(4))) float floatx4;

__device__ __forceinline__ float relu_(float v) { return fmaxf(v, 0.f); }

__device__ __forceinline__ uint32_t f2bf(float f) {
    uint32_t u = __float_as_uint(f);
    return (u + 0x7FFFu + ((u >> 16) & 1u)) >> 16;
}
__device__ __forceinline__ float bf2f(uint32_t h) { return __uint_as_float(h << 16); }

__device__ __constant__ uint32_t PRS[6] = {1u, 2654435761u, 805459861u, 3674653429u, 2097192037u, 1434869437u};
__device__ __constant__ float RESF[16]  = {16.f,20.f,25.f,32.f,40.f,50.f,64.f,80.f,101.f,128.f,161.f,203.f,256.f,322.f,406.f,512.f};
__device__ __constant__ float GRIDF[16] = {1.f/16.f,1.f/20.f,1.f/25.f,1.f/32.f,1.f/40.f,1.f/50.f,1.f/64.f,1.f/80.f,
                                           1.f/101.f,1.f/128.f,1.f/161.f,1.f/203.f,1.f/256.f,1.f/322.f,1.f/406.f,1.f/512.f};

// ---------------- binning kernels ----------------
__global__ void k_count(const int* __restrict__ lid, int n, int* __restrict__ cnt) {
    __shared__ int h4[4];
    int i = blockIdx.x * blockDim.x + threadIdx.x;
    if (threadIdx.x < 4) h4[threadIdx.x] = 0;
    __syncthreads();
    if (i < n) atomicAdd(&h4[lid[i] & 3], 1);
    __syncthreads();
    if (threadIdx.x < 4) atomicAdd(&cnt[threadIdx.x], h4[threadIdx.x]);
}

__global__ void k_offsets(const int* __restrict__ cnt, int* __restrict__ cursor) {
    if (threadIdx.x == 0 && blockIdx.x == 0) {
        int off = 0;
        for (int k = 0; k < 4; k++) {
            cursor[k] = off;
            off = (off + cnt[k] + 63) & ~63;
        }
    }
}

__global__ void k_scatter(const int* __restrict__ lid, int n, int* __restrict__ cursor, int* __restrict__ perm) {
    int i = blockIdx.x * blockDim.x + threadIdx.x;
    if (i >= n) return;
    int lane = threadIdx.x & 63;
    int c = lid[i] & 3;
    unsigned long long m0 = __ballot(c == 0), m1 = __ballot(c == 1);
    unsigned long long m2 = __ballot(c == 2), m3 = __ballot(c == 3);
    unsigned long long mc = (c == 0) ? m0 : (c == 1) ? m1 : (c == 2) ? m2 : m3;
    int rank = __popcll(mc & ((1ull << lane) - 1ull));
    int cntl = (lane == 0) ? __popcll(m0) : (lane == 1) ? __popcll(m1) : (lane == 2) ? __popcll(m2) : __popcll(m3);
    int basev = 0;
    if (lane < 4) basev = atomicAdd(&cursor[lane], cntl);
    int base = __shfl(basev, c, 64);
    perm[base + rank] = i;
}

// ---------------- pack embedding table to bf16: T[l][g] = (bf16(e.x), bf16(e.y)) ----------------
__global__ __launch_bounds__(256) void k_packtab(const float* __restrict__ emb, uint32_t* __restrict__ T) {
    const int i = blockIdx.x * 256 + threadIdx.x;
    float2 e = ((const float2*)emb)[i];
    T[i] = f2bf(e.x) | (f2bf(e.y) << 16);
}

// ---------------- weight prep: transpose + bf16 ----------------
// blocks 0..191: Wres [c][ib][k][n] fp32 -> Wrt [c][ib][n][k] bf16 (64x64 tiles)
// blocks 192..195: W0 [c][32][256] fp32 -> W0t [c][256][32] bf16
__global__ __launch_bounds__(256) void k_prep(const float* __restrict__ Wres, const float* __restrict__ W0,
                                              uint16_t* __restrict__ Wrt, uint16_t* __restrict__ W0t) {
    __shared__ float sm[64 * 65 > 32 * 257 ? 64 * 65 : 32 * 257];
    const int t = threadIdx.x;
    const int bid = blockIdx.x;
    if (bid < 192) {
        const int c = bid / 48, rem = bid % 48, ib = rem / 16, tile = rem % 16;
        const int n0 = (tile / 4) * 64, k0 = (tile % 4) * 64;
        const float* src = Wres + (size_t)(c * 3 + ib) * 65536;
        for (int i = 0; i < 16; i++) {
            int idx = t + 256 * i, r = idx >> 6, cc = idx & 63;
            sm[r * 65 + cc] = src[(size_t)(k0 + r) * 256 + n0 + cc];
        }
        __syncthreads();
        uint16_t* dst = Wrt + (size_t)(c * 3 + ib) * 65536;
        for (int i = 0; i < 16; i++) {
            int idx = t + 256 * i, rn = idx >> 6, ck = idx & 63;
            dst[(size_t)(n0 + rn) * 256 + k0 + ck] = (uint16_t)f2bf(sm[ck * 65 + rn]);
        }
    } else {
        const int c = bid - 192;
        for (int i = 0; i < 32; i++) {
            int idx = t + 256 * i, k = idx >> 8, n = idx & 255;
            sm[k * 257 + n] = W0[(size_t)c * 8192 + idx];
        }
        __syncthreads();
        for (int i = 0; i < 32; i++) {
            int idx = t + 256 * i, n = idx >> 5, k = idx & 31;
            W0t[(size_t)c * 8192 + idx] = (uint16_t)f2bf(sm[k * 257 + n]);
        }
    }
}

// ---------------- encode kernel: one level per block, level -> XCD pinned ----------------
// Gathers from the bf16 pair table. Dim0's prime is 1, so for even bl0 the two dim0
// vertices are XOR-1 adjacent table entries -> one 8B load serves both (32 reqs);
// odd bl0 does 64 4B loads. Avg 48 reqs/point-level (was 64 x 8B).
__global__ __launch_bounds__(256, 4) void k_encode(
    const float* __restrict__ x, const uint32_t* __restrict__ T,
    uint32_t* __restrict__ encP, int B)
{
    __shared__ float xs[256 * 6];
    const int t = threadIdx.x;
    const int NC8 = (B >> 8) << 3;
    const int pass = (blockIdx.x >= NC8) ? 1 : 0;
    const int rem  = blockIdx.x - pass * NC8;
    const int l    = (rem & 7) + (pass << 3);
    const int chunk = rem >> 3;
    const int pbase = chunk << 8;

    for (int idx = t; idx < 256 * 6; idx += 256) {
        float v = x[(size_t)pbase * 6 + idx];
        xs[idx] = fminf(fmaxf(v, 0.f), 1.f);
    }
    __syncthreads();

    const float res  = RESF[l];
    const float grid = GRIDF[l];
    float wv[6]; uint32_t ua[6], ub[6];
    #pragma unroll
    for (int d = 0; d < 6; d++) {
        float xv  = xs[t * 6 + d];
        float blf = floorf(xv * res);
        float w   = (xv - blf * grid) / (grid + 1e-6f);
        wv[d] = fminf(fmaxf(w, 0.f), 1.f);
        uint32_t uu = (uint32_t)(int)blf * PRS[d];
        ua[d] = uu; ub[d] = uu + PRS[d];
    }
    // v = (i<<4)|(j<<2)|k. Hash: dims (0,1)<-i, (2,3)<-j, (4,5)<-k (MSB-first).
    // Weights LSB-first: hash-dim0<->wv[5], dim1<->wv[4], dim2<->wv[3], dim3<->wv[2],
    // dim4<->wv[1], dim5<->wv[0] — faithful to the reference's bit-order mismatch.
    uint32_t HJ[4], HK[4]; float WJ[4], WK[4];
    #pragma unroll
    for (int q = 0; q < 4; q++) {
        const int b1 = (q >> 1) & 1, bb = q & 1;
        HJ[q] = (b1 ? ub[2] : ua[2]) ^ (bb ? ub[3] : ua[3]);
        HK[q] = (b1 ? ub[4] : ua[4]) ^ (bb ? ub[5] : ua[5]);
        WJ[q] = (bb ? wv[2] : 1.f - wv[2]) * (b1 ? wv[3] : 1.f - wv[3]);
        WK[q] = (bb ? wv[0] : 1.f - wv[0]) * (b1 ? wv[1] : 1.f - wv[1]);
    }
    const uint32_t D1[2] = {ua[1], ub[1]};
    const float   WD1[2] = {1.f - wv[4], wv[4]};
    const float w5a = 1.f - wv[5], w5b = wv[5];   // dim0 beta weights
    const uint32_t bl0 = ua[0];                   // prime = 1
    const uint32_t* __restrict__ Tl = T + (size_t)l * HTABLE;

    float f0 = 0.f, f1 = 0.f;
    if (!(bl0 & 1u)) {
        // even: pair {bl0^S, (bl0+1)^S} = {h, h^1} -> one aligned 8B load
        #pragma unroll
        for (int j1 = 0; j1 < 2; j1++) {
            #pragma unroll
            for (int j = 0; j < 4; j++) {
                const uint32_t Sj = D1[j1] ^ HJ[j];
                const float   wj = WD1[j1] * WJ[j];
                #pragma unroll
                for (int k = 0; k < 4; k++) {
                    const uint32_t h = (bl0 ^ Sj ^ HK[k]) & TMASK;
                    const float wS = wj * WK[k];
                    const uint2 pr = *(const uint2*)(Tl + (h & ~1u));
                    const uint32_t pa = (h & 1u) ? pr.y : pr.x;   // E[h]     (beta=0)
                    const uint32_t pb = (h & 1u) ? pr.x : pr.y;   // E[h^1]   (beta=1)
                    const float e0x = __uint_as_float(pa << 16),  e0y = __uint_as_float(pa & 0xFFFF0000u);
                    const float e1x = __uint_as_float(pb << 16),  e1y = __uint_as_float(pb & 0xFFFF0000u);
                    f0 = fmaf(wS, fmaf(w5a, e0x, w5b * e1x), f0);
                    f1 = fmaf(wS, fmaf(w5a, e0y, w5b * e1y), f1);
                }
            }
        }
    } else {
        const uint32_t bl0b = bl0 + 1u;
        #pragma unroll
        for (int j1 = 0; j1 < 2; j1++) {
            #pragma unroll
            for (int j = 0; j < 4; j++) {
                const uint32_t Sj = D1[j1] ^ HJ[j];
                const float   wj = WD1[j1] * WJ[j];
                #pragma unroll
                for (int k = 0; k < 4; k++) {
                    const uint32_t S = Sj ^ HK[k];
                    const float wS = wj * WK[k];
                    const uint32_t pa = Tl[(bl0  ^ S) & TMASK];
                    const uint32_t pb = Tl[(bl0b ^ S) & TMASK];
                    const float e0x = __uint_as_float(pa << 16),  e0y = __uint_as_float(pa & 0xFFFF0000u);
                    const float e1x = __uint_as_float(pb << 16),  e1y = __uint_as_float(pb & 0xFFFF0000u);
                    f0 = fmaf(wS, fmaf(w5a, e0x, w5b * e1x), f0);
                    f1 = fmaf(wS, fmaf(w5a, e0y, w5b * e1y), f1);
                }
            }
        }
    }
    encP[(size_t)l * B + pbase + t] = f2bf(f0) | (f2bf(f1) << 16);
}

// ---------------- MFMA MLP ----------------
// Per block: 64 class-uniform points. GEMMs computed as D[n=neuron][m=point] = W^T . H
// so C/D regs (4 consecutive neurons) are k-contiguous for the next layer's B operand.
// Wave wv owns neurons [wv*64, wv*64+64); fp32 residual carry lives in h_reg.
__global__ __launch_bounds__(256, 2) void k_mlp2(
    const int* __restrict__ lid, const uint32_t* __restrict__ encP,
    const uint16_t* __restrict__ W0t, const float* __restrict__ b0,
    const uint16_t* __restrict__ Wrt, const float* __restrict__ bres,
    const float* __restrict__ scales, const float* __restrict__ Wout, const float* __restrict__ bout,
    const int* __restrict__ perm, float* __restrict__ out, int B)
{
    __shared__ uint16_t hB[64 * KSTR];     // 33792 B  H as [point][k] bf16
    __shared__ uint16_t encB[64 * KE];     //  5120 B  enc as [point][k32] bf16
    __shared__ float    bs[256];           //  per-layer bias / Wout stage
    __shared__ float    outP[256];
    __shared__ int      permL[TILE];

    const int t  = threadIdx.x;
    const int lane = t & 63;
    const int wv = t >> 6;          // wave id: neuron slice
    const int mi = lane & 15;       // point within 16-col
    const int q  = lane >> 4;       // quad

    if (t < TILE) permL[t] = perm[(size_t)blockIdx.x * TILE + t];
    __syncthreads();
    const int g0 = permL[0];
    if (g0 < 0) return;
    const int c = lid[g0] & 3;

    // stage enc [point][k=2l..2l+1] and b0
    bs[t] = b0[c * 256 + t];
    for (int idx = t; idx < 16 * 64; idx += 256) {
        const int l = idx >> 6, pp = idx & 63;
        const int gi = permL[pp];
        ((uint32_t*)encB)[pp * (KE / 2) + l] = (gi >= 0) ? encP[(size_t)l * B + gi] : 0u;
    }
    __syncthreads();

    floatx4 acc[4][4];
    floatx4 h_reg[4][4];

    // ---- layer 0: D = W0^T(256x32) . enc(32x64)
    {
        #pragma unroll
        for (int mt = 0; mt < 4; mt++)
            #pragma unroll
            for (int nt = 0; nt < 4; nt++) acc[mt][nt] = (floatx4){0.f, 0.f, 0.f, 0.f};
        const short8* Wp = (const short8*)(W0t + (size_t)c * 8192);
        short8 A[4], Bf[4];
        #pragma unroll
        for (int mt = 0; mt < 4; mt++) A[mt] = Wp[(wv * 64 + mt * 16 + mi) * 4 + q];
        #pragma unroll
        for (int nt = 0; nt < 4; nt++) Bf[nt] = *(const short8*)&encB[(nt * 16 + mi) * KE + q * 8];
        #pragma unroll
        for (int mt = 0; mt < 4; mt++)
            #pragma unroll
            for (int nt = 0; nt < 4; nt++)
                acc[mt][nt] = __builtin_amdgcn_mfma_f32_16x16x32_bf16(A[mt], Bf[nt], acc[mt][nt], 0, 0, 0);
        // h = relu(u + b0); write bf16 to hB
        #pragma unroll
        for (int mt = 0; mt < 4; mt++) {
            const int nb = wv * 64 + mt * 16 + q * 4;
            #pragma unroll
            for (int nt = 0; nt < 4; nt++) {
                floatx4 u = acc[mt][nt], h;
                h[0] = relu_(u[0] + bs[nb + 0]); h[1] = relu_(u[1] + bs[nb + 1]);
                h[2] = relu_(u[2] + bs[nb + 2]); h[3] = relu_(u[3] + bs[nb + 3]);
                h_reg[mt][nt] = h;
                uint2 pk; pk.x = f2bf(h[0]) | (f2bf(h[1]) << 16); pk.y = f2bf(h[2]) | (f2bf(h[3]) << 16);
                *(uint2*)&hB[(nt * 16 + mi) * KSTR + nb] = pk;
            }
        }
    }
    __syncthreads();

    // ---- 3 scaled residual blocks
    #pragma unroll 1
    for (int ib = 0; ib < 3; ib++) {
        bs[t] = bres[(size_t)((c * 3 + ib) << 8) + t];   // read after the post-MFMA barrier
        const float s = scales[c * 3 + ib];
        #pragma unroll
        for (int mt = 0; mt < 4; mt++)
            #pragma unroll
            for (int nt = 0; nt < 4; nt++) acc[mt][nt] = (floatx4){0.f, 0.f, 0.f, 0.f};

        const short8* Wp = (const short8*)(Wrt + (size_t)(c * 3 + ib) * 65536);
        short8 Acur[4], Anext[4], Bf[4];
        #pragma unroll
        for (int mt = 0; mt < 4; mt++) Acur[mt] = Wp[(wv * 64 + mt * 16 + mi) * 32 + q];
        #pragma unroll 1
        for (int ks = 0; ks < 8; ks++) {
            #pragma unroll
            for (int nt = 0; nt < 4; nt++)
                Bf[nt] = *(const short8*)&hB[(nt * 16 + mi) * KSTR + ks * 32 + q * 8];
            if (ks < 7) {
                #pragma unroll
                for (int mt = 0; mt < 4; mt++)
                    Anext[mt] = Wp[(wv * 64 + mt * 16 + mi) * 32 + (ks + 1) * 4 + q];
            }
            #pragma unroll
            for (int mt = 0; mt < 4; mt++)
                #pragma unroll
                for (int nt = 0; nt < 4; nt++)
                    acc[mt][nt] = __builtin_amdgcn_mfma_f32_16x16x32_bf16(Acur[mt], Bf[nt], acc[mt][nt], 0, 0, 0);
            #pragma unroll
            for (int mt = 0; mt < 4; mt++) Acur[mt] = Anext[mt];
        }
        __syncthreads();   // hB reads done; bs staged
        #pragma unroll
        for (int mt = 0; mt < 4; mt++) {
            const int nb = wv * 64 + mt * 16 + q * 4;
            #pragma unroll
            for (int nt = 0; nt < 4; nt++) {
                floatx4 u = acc[mt][nt];
                floatx4 h = h_reg[mt][nt];
                h[0] = fmaf(s, relu_(u[0] + bs[nb + 0]), h[0]);
                h[1] = fmaf(s, relu_(u[1] + bs[nb + 1]), h[1]);
                h[2] = fmaf(s, relu_(u[2] + bs[nb + 2]), h[2]);
                h[3] = fmaf(s, relu_(u[3] + bs[nb + 3]), h[3]);
                h_reg[mt][nt] = h;
                if (ib < 2) {
                    uint2 pk; pk.x = f2bf(h[0]) | (f2bf(h[1]) << 16); pk.y = f2bf(h[2]) | (f2bf(h[3]) << 16);
                    *(uint2*)&hB[(nt * 16 + mi) * KSTR + nb] = pk;
                }
            }
        }
        if (ib < 2) __syncthreads();
    }

    // ---- output layer: out[p] = sum_n h[n][p] * Wout[n] + bout
    __syncthreads();
    bs[t] = Wout[c * 256 + t];
    __syncthreads();
    float po[4] = {0.f, 0.f, 0.f, 0.f};
    #pragma unroll
    for (int mt = 0; mt < 4; mt++) {
        const int nb = wv * 64 + mt * 16 + q * 4;
        const float w0v = bs[nb + 0], w1v = bs[nb + 1], w2v = bs[nb + 2], w3v = bs[nb + 3];
        #pragma unroll
        for (int nt = 0; nt < 4; nt++) {
            const floatx4 h = h_reg[mt][nt];
            po[nt] += h[0] * w0v + h[1] * w1v + h[2] * w2v + h[3] * w3v;
        }
    }
    #pragma unroll
    for (int nt = 0; nt < 4; nt++) {
        float v = po[nt];
        v += __shfl_xor(v, 16, 64);
        v += __shfl_xor(v, 32, 64);
        if (q == 0) outP[wv * 64 + nt * 16 + mi] = v;
    }
    __syncthreads();
    if (t < TILE) {
        float r = outP[t] + outP[64 + t] + outP[128 + t] + outP[192 + t] + bout[c];
        const int gi = permL[t];
        if (gi >= 0) out[gi] = r;
    }
}

extern "C" void kernel_launch(void* const* d_in, const int* in_sizes, int n_in,
                              void* d_out, int out_size, void* d_ws, size_t ws_size,
                              hipStream_t stream) {
    const float* x      = (const float*)d_in[0];
    const int*   lid    = (const int*)  d_in[1];
    const float* emb    = (const float*)d_in[2];
    const float* W0     = (const float*)d_in[3];
    const float* b0     = (const float*)d_in[4];
    const float* Wres   = (const float*)d_in[5];
    const float* bres   = (const float*)d_in[6];
    const float* scales = (const float*)d_in[7];
    const float* Wout   = (const float*)d_in[8];
    const float* bout   = (const float*)d_in[9];
    float* out = (float*)d_out;

    const int B = in_sizes[1];                          // 524288 points
    int* cnt    = (int*)d_ws;                           // [0..3]
    int* cursor = cnt + 4;                              // [4..7]
    int* perm   = cnt + 64;                             // +256 B, padded permutation (~2.1 MB)
    uint16_t* W0t = (uint16_t*)((char*)d_ws + 2228224); // +2.125 MB: [4][256][32] bf16 (64 KB)
    uint16_t* Wrt = (uint16_t*)((char*)d_ws + 2359296); // +2.25 MB: [4][3][256][256] bf16 (1.5 MB)
    uint32_t* encP = (uint32_t*)((char*)d_ws + (4u << 20));   // +4 MB: [16][B] packed bf16 pairs (32 MB)
    uint32_t* T    = (uint32_t*)((char*)d_ws + (36u << 20));  // +36 MB: bf16 pair table [16][2^19] (32 MB)
    const int nblk = B / TILE + 4;                      // 8196

    (void)hipMemsetAsync(d_ws, 0, 32, stream);
    (void)hipMemsetAsync(perm, 0xFF, (size_t)nblk * TILE * sizeof(int), stream);
    k_packtab<<<(16 * (int)HTABLE) / 256, 256, 0, stream>>>(emb, T);
    k_prep   <<<196, 256, 0, stream>>>(Wres, W0, Wrt, W0t);
    k_count  <<<B / 256, 256, 0, stream>>>(lid, B, cnt);
    k_offsets<<<1, 64, 0, stream>>>(cnt, cursor);
    k_scatter<<<B / 256, 256, 0, stream>>>(lid, B, cursor, perm);
    k_encode <<<(B / 256) * 16, 256, 0, stream>>>(x, T, encP, B);
    k_mlp2   <<<nblk, 256, 0, stream>>>(lid, encP, W0t, b0, Wrt, bres, scales, Wout, bout, perm, out, B);
}